// Round 1
// baseline (798.293 us; speedup 1.0000x reference)
//
#include <hip/hip_runtime.h>

// Problem constants (fixed by setup_inputs)
constexpr int B = 16, C = 8, H = 512, W = 512;
constexpr int HW = H * W;

// ---------------------------------------------------------------------------
// Kernel 1: q/k 1x1-conv projections.  q[b,p] = bq + sum_c Wq[c]*x[b,c,p]
// ---------------------------------------------------------------------------
__global__ __launch_bounds__(256) void qk_kernel(
    const float* __restrict__ x, const float* __restrict__ Wq, const float* __restrict__ bq,
    const float* __restrict__ Wk, const float* __restrict__ bk,
    float* __restrict__ q, float* __restrict__ k)
{
    int t = blockIdx.x * 256 + threadIdx.x;        // over B*HW/4
    int b = t / (HW / 4);
    int p = (t % (HW / 4)) * 4;
    const float* xb = x + (size_t)b * C * HW + p;
    float wq[8], wk[8];
#pragma unroll
    for (int c = 0; c < 8; ++c) { wq[c] = Wq[c]; wk[c] = Wk[c]; }
    float bq0 = bq[0], bk0 = bk[0];
    float4 aq = make_float4(bq0, bq0, bq0, bq0);
    float4 ak = make_float4(bk0, bk0, bk0, bk0);
#pragma unroll
    for (int c = 0; c < 8; ++c) {
        float4 xv = *reinterpret_cast<const float4*>(xb + (size_t)c * HW);
        aq.x = fmaf(wq[c], xv.x, aq.x); aq.y = fmaf(wq[c], xv.y, aq.y);
        aq.z = fmaf(wq[c], xv.z, aq.z); aq.w = fmaf(wq[c], xv.w, aq.w);
        ak.x = fmaf(wk[c], xv.x, ak.x); ak.y = fmaf(wk[c], xv.y, ak.y);
        ak.z = fmaf(wk[c], xv.z, ak.z); ak.w = fmaf(wk[c], xv.w, ak.w);
    }
    *reinterpret_cast<float4*>(q + (size_t)b * HW + p) = aq;
    *reinterpret_cast<float4*>(k + (size_t)b * HW + p) = ak;
}

// ---------------------------------------------------------------------------
// Kernel 2: attn[b,i,j] = sum_w q[b,i,w] * k[b,j,w]   (NT GEMM, 512x512x512/batch)
// 128x128 tile, BK=16, 256 threads, 8x8 microtile.
// ---------------------------------------------------------------------------
__global__ __launch_bounds__(256) void qk_gemm_kernel(
    const float* __restrict__ q, const float* __restrict__ k, float* __restrict__ attn)
{
    __shared__ float As[16][132];
    __shared__ float Bs[16][132];
    int b  = blockIdx.z;
    int i0 = blockIdx.y * 128;
    int j0 = blockIdx.x * 128;
    const float* Qb = q + (size_t)b * HW;
    const float* Kb = k + (size_t)b * HW;
    int t  = threadIdx.x;
    int tx = t % 16, ty = t / 16;
    int sc = t % 16;          // k-col within tile
    int sr0 = t / 16;         // row base 0..15
    float acc[8][8] = {};
    for (int w0 = 0; w0 < W; w0 += 16) {
        __syncthreads();
#pragma unroll
        for (int p = 0; p < 8; ++p) {
            int r = sr0 + 16 * p;
            As[sc][r] = Qb[(size_t)(i0 + r) * W + w0 + sc];
            Bs[sc][r] = Kb[(size_t)(j0 + r) * W + w0 + sc];
        }
        __syncthreads();
#pragma unroll
        for (int kk = 0; kk < 16; ++kk) {
            float a[8], bb[8];
            *reinterpret_cast<float4*>(&a[0])  = *reinterpret_cast<const float4*>(&As[kk][ty * 8]);
            *reinterpret_cast<float4*>(&a[4])  = *reinterpret_cast<const float4*>(&As[kk][ty * 8 + 4]);
            *reinterpret_cast<float4*>(&bb[0]) = *reinterpret_cast<const float4*>(&Bs[kk][tx * 8]);
            *reinterpret_cast<float4*>(&bb[4]) = *reinterpret_cast<const float4*>(&Bs[kk][tx * 8 + 4]);
#pragma unroll
            for (int m = 0; m < 8; ++m)
#pragma unroll
                for (int n = 0; n < 8; ++n)
                    acc[m][n] = fmaf(a[m], bb[n], acc[m][n]);
        }
    }
    float* Cb = attn + (size_t)b * H * H;
#pragma unroll
    for (int m = 0; m < 8; ++m) {
        int row = i0 + ty * 8 + m;
        *reinterpret_cast<float4*>(&Cb[(size_t)row * H + j0 + tx * 8]) =
            make_float4(acc[m][0], acc[m][1], acc[m][2], acc[m][3]);
        *reinterpret_cast<float4*>(&Cb[(size_t)row * H + j0 + tx * 8 + 4]) =
            make_float4(acc[m][4], acc[m][5], acc[m][6], acc[m][7]);
    }
}

// ---------------------------------------------------------------------------
// Kernel 3: row softmax over attn[b,i,:] (512 cols), one wave per row.
// ---------------------------------------------------------------------------
__global__ __launch_bounds__(256) void softmax_kernel(float* __restrict__ attn)
{
    int gid  = blockIdx.x * 256 + threadIdx.x;
    int row  = gid >> 6;
    int lane = gid & 63;
    float* rp = attn + (size_t)row * H;
    float4 v0 = *reinterpret_cast<float4*>(&rp[lane * 8]);
    float4 v1 = *reinterpret_cast<float4*>(&rp[lane * 8 + 4]);
    float m = fmaxf(fmaxf(fmaxf(v0.x, v0.y), fmaxf(v0.z, v0.w)),
                    fmaxf(fmaxf(v1.x, v1.y), fmaxf(v1.z, v1.w)));
#pragma unroll
    for (int off = 32; off > 0; off >>= 1) m = fmaxf(m, __shfl_xor(m, off, 64));
    v0.x = __expf(v0.x - m); v0.y = __expf(v0.y - m);
    v0.z = __expf(v0.z - m); v0.w = __expf(v0.w - m);
    v1.x = __expf(v1.x - m); v1.y = __expf(v1.y - m);
    v1.z = __expf(v1.z - m); v1.w = __expf(v1.w - m);
    float s = v0.x + v0.y + v0.z + v0.w + v1.x + v1.y + v1.z + v1.w;
#pragma unroll
    for (int off = 32; off > 0; off >>= 1) s += __shfl_xor(s, off, 64);
    float inv = 1.0f / s;
    v0.x *= inv; v0.y *= inv; v0.z *= inv; v0.w *= inv;
    v1.x *= inv; v1.y *= inv; v1.z *= inv; v1.w *= inv;
    *reinterpret_cast<float4*>(&rp[lane * 8])     = v0;
    *reinterpret_cast<float4*>(&rp[lane * 8 + 4]) = v1;
}

// ---------------------------------------------------------------------------
// Kernel 4: out[b,c,i,w] = sum_j attn[b,i,j] * v[b,c,j,w] + (bias via softmax-sum=1)
// where v[b,c,j,w] = sum_c' Wv[c,c'] x[b,c',j,w]  is mixed on-the-fly during
// B-operand staging (v never materialized).  Same 128x128x16 tiling.
// ---------------------------------------------------------------------------
__global__ __launch_bounds__(256) void pv_gemm_kernel(
    const float* __restrict__ attn, const float* __restrict__ x,
    const float* __restrict__ Wv, const float* __restrict__ bv, float* __restrict__ out)
{
    __shared__ float As[16][132];
    __shared__ float Bs[16][132];
    int bc = blockIdx.z;            // b*8 + c
    int b  = bc >> 3, c = bc & 7;
    int i0 = blockIdx.y * 128;
    int w0 = blockIdx.x * 128;
    const float* Ab = attn + (size_t)b * H * H;
    const float* xb = x + (size_t)b * C * HW;
    float wv[8];
#pragma unroll
    for (int cc = 0; cc < 8; ++cc) wv[cc] = Wv[c * 8 + cc];
    int t  = threadIdx.x;
    int tx = t % 16, ty = t / 16;
    int ac = t % 16, ar0 = t / 16;   // A staging
    int bn = t % 128, br0 = t / 128; // B staging (0..1)
    float acc[8][8] = {};
    for (int j0 = 0; j0 < H; j0 += 16) {
        __syncthreads();
#pragma unroll
        for (int p = 0; p < 8; ++p) {
            int r = ar0 + 16 * p;
            As[ac][r] = Ab[(size_t)(i0 + r) * H + j0 + ac];
        }
#pragma unroll
        for (int p = 0; p < 8; ++p) {
            int jj = br0 + 2 * p;
            const float* xp = xb + (size_t)(j0 + jj) * W + w0 + bn;
            float v = 0.f;
#pragma unroll
            for (int cc = 0; cc < 8; ++cc) v = fmaf(wv[cc], xp[(size_t)cc * HW], v);
            Bs[jj][bn] = v;
        }
        __syncthreads();
#pragma unroll
        for (int kk = 0; kk < 16; ++kk) {
            float a[8], bb[8];
            *reinterpret_cast<float4*>(&a[0])  = *reinterpret_cast<const float4*>(&As[kk][ty * 8]);
            *reinterpret_cast<float4*>(&a[4])  = *reinterpret_cast<const float4*>(&As[kk][ty * 8 + 4]);
            *reinterpret_cast<float4*>(&bb[0]) = *reinterpret_cast<const float4*>(&Bs[kk][tx * 8]);
            *reinterpret_cast<float4*>(&bb[4]) = *reinterpret_cast<const float4*>(&Bs[kk][tx * 8 + 4]);
#pragma unroll
            for (int m = 0; m < 8; ++m)
#pragma unroll
                for (int n = 0; n < 8; ++n)
                    acc[m][n] = fmaf(a[m], bb[n], acc[m][n]);
        }
    }
    float bias = bv[c];
    float* outp = out + (size_t)bc * HW;
#pragma unroll
    for (int m = 0; m < 8; ++m) {
        int row = i0 + ty * 8 + m;
        *reinterpret_cast<float4*>(&outp[(size_t)row * W + w0 + tx * 8]) =
            make_float4(acc[m][0] + bias, acc[m][1] + bias, acc[m][2] + bias, acc[m][3] + bias);
        *reinterpret_cast<float4*>(&outp[(size_t)row * W + w0 + tx * 8 + 4]) =
            make_float4(acc[m][4] + bias, acc[m][5] + bias, acc[m][6] + bias, acc[m][7] + bias);
    }
}

extern "C" void kernel_launch(void* const* d_in, const int* in_sizes, int n_in,
                              void* d_out, int out_size, void* d_ws, size_t ws_size,
                              hipStream_t stream) {
    const float* x  = (const float*)d_in[0];
    const float* Wq = (const float*)d_in[1];
    const float* bq = (const float*)d_in[2];
    const float* Wk = (const float*)d_in[3];
    const float* bk = (const float*)d_in[4];
    const float* Wv = (const float*)d_in[5];
    const float* bv = (const float*)d_in[6];
    float* out = (float*)d_out;

    // workspace layout: q[B*HW] | k[B*HW] | attn[B*H*H]  (3 * 16.8 MB = 50.4 MB)
    float* q    = (float*)d_ws;
    float* k    = q + (size_t)B * HW;
    float* attn = k + (size_t)B * HW;

    qk_kernel<<<B * HW / 4 / 256, 256, 0, stream>>>(x, Wq, bq, Wk, bk, q, k);
    qk_gemm_kernel<<<dim3(H / 128, H / 128, B), 256, 0, stream>>>(q, k, attn);
    softmax_kernel<<<(B * H * 64) / 256, 256, 0, stream>>>(attn);
    pv_gemm_kernel<<<dim3(W / 128, H / 128, B * C), 256, 0, stream>>>(attn, x, Wv, bv, out);
}

// Round 2
// 378.301 us; speedup vs baseline: 2.1102x; 2.1102x over previous
//
#include <hip/hip_runtime.h>

constexpr int B = 16, C = 8, H = 512, W = 512;
constexpr int HW = H * W;

typedef short bf16x8 __attribute__((ext_vector_type(8)));
typedef float f32x4 __attribute__((ext_vector_type(4)));

__device__ __forceinline__ unsigned short f2bf(float f) {
    union { float f; unsigned u; } v; v.f = f;
    unsigned r = (v.u + 0x7FFFu + ((v.u >> 16) & 1u)) >> 16;
    return (unsigned short)r;
}

// ---------------------------------------------------------------------------
// Kernel 1: fused q/k/v 1x1 convs. q,k fp32; v bf16 in [b][c][j][w] (no bias:
// softmax rows sum to 1, so bv is added once in the PV epilogue).
// ---------------------------------------------------------------------------
__global__ __launch_bounds__(256) void qkv_kernel(
    const float* __restrict__ x, const float* __restrict__ Wq, const float* __restrict__ bq,
    const float* __restrict__ Wk, const float* __restrict__ bk, const float* __restrict__ Wv,
    float* __restrict__ q, float* __restrict__ k, unsigned short* __restrict__ v)
{
    int t = blockIdx.x * 256 + threadIdx.x;        // over B*HW/4
    int b = t / (HW / 4);
    int p = (t % (HW / 4)) * 4;
    const float* xb = x + (size_t)b * C * HW + p;
    float4 aq = make_float4(bq[0], bq[0], bq[0], bq[0]);
    float4 ak = make_float4(bk[0], bk[0], bk[0], bk[0]);
    float vacc[8][4] = {};
#pragma unroll
    for (int cc = 0; cc < 8; ++cc) {
        float4 xv = *reinterpret_cast<const float4*>(xb + (size_t)cc * HW);
        float wq = Wq[cc], wk = Wk[cc];
        aq.x = fmaf(wq, xv.x, aq.x); aq.y = fmaf(wq, xv.y, aq.y);
        aq.z = fmaf(wq, xv.z, aq.z); aq.w = fmaf(wq, xv.w, aq.w);
        ak.x = fmaf(wk, xv.x, ak.x); ak.y = fmaf(wk, xv.y, ak.y);
        ak.z = fmaf(wk, xv.z, ak.z); ak.w = fmaf(wk, xv.w, ak.w);
#pragma unroll
        for (int c = 0; c < 8; ++c) {
            float wv = Wv[c * 8 + cc];
            vacc[c][0] = fmaf(wv, xv.x, vacc[c][0]);
            vacc[c][1] = fmaf(wv, xv.y, vacc[c][1]);
            vacc[c][2] = fmaf(wv, xv.z, vacc[c][2]);
            vacc[c][3] = fmaf(wv, xv.w, vacc[c][3]);
        }
    }
    *reinterpret_cast<float4*>(q + (size_t)b * HW + p) = aq;
    *reinterpret_cast<float4*>(k + (size_t)b * HW + p) = ak;
#pragma unroll
    for (int c = 0; c < 8; ++c) {
        ushort4 pk;
        pk.x = f2bf(vacc[c][0]); pk.y = f2bf(vacc[c][1]);
        pk.z = f2bf(vacc[c][2]); pk.w = f2bf(vacc[c][3]);
        *reinterpret_cast<ushort4*>(v + ((size_t)(b * 8 + c)) * HW + p) = pk;
    }
}

// ---------------------------------------------------------------------------
// Kernel 2: batched 64x64 LDS transpose v[b][c][j][w] -> vt[b][c][w][j] (bf16)
// ---------------------------------------------------------------------------
__global__ __launch_bounds__(256) void transpose_kernel(
    const unsigned short* __restrict__ v, unsigned short* __restrict__ vt)
{
    __shared__ int lds[64][65];
    int bc = blockIdx.y;                 // b*C + c
    int j0 = (blockIdx.x >> 3) * 64;
    int w0 = (blockIdx.x & 7) * 64;
    const unsigned short* vp = v + (size_t)bc * HW;
    unsigned short* vtp = vt + (size_t)bc * HW;
    int t = threadIdx.x;
    int jr = t >> 4, c4 = (t & 15) * 4;
#pragma unroll
    for (int rr = 0; rr < 4; ++rr) {
        int j = jr + rr * 16;
        ushort4 d = *reinterpret_cast<const ushort4*>(vp + (size_t)(j0 + j) * W + w0 + c4);
        lds[j][c4 + 0] = d.x; lds[j][c4 + 1] = d.y;
        lds[j][c4 + 2] = d.z; lds[j][c4 + 3] = d.w;
    }
    __syncthreads();
#pragma unroll
    for (int rr = 0; rr < 4; ++rr) {
        int w = jr + rr * 16;
        ushort4 d;
        d.x = (unsigned short)lds[c4 + 0][w];
        d.y = (unsigned short)lds[c4 + 1][w];
        d.z = (unsigned short)lds[c4 + 2][w];
        d.w = (unsigned short)lds[c4 + 3][w];
        *reinterpret_cast<ushort4*>(vtp + (size_t)(w0 + w) * H + j0 + c4) = d;
    }
}

// ---------------------------------------------------------------------------
// Kernel 3: attn[b,i,j] = sum_w q[b,i,w]*k[b,j,w]  (fp32 VALU, unchanged)
// ---------------------------------------------------------------------------
__global__ __launch_bounds__(256) void qk_gemm_kernel(
    const float* __restrict__ q, const float* __restrict__ k, float* __restrict__ attn)
{
    __shared__ float As[16][132];
    __shared__ float Bs[16][132];
    int b  = blockIdx.z;
    int i0 = blockIdx.y * 128;
    int j0 = blockIdx.x * 128;
    const float* Qb = q + (size_t)b * HW;
    const float* Kb = k + (size_t)b * HW;
    int t  = threadIdx.x;
    int tx = t % 16, ty = t / 16;
    int sc = t % 16, sr0 = t / 16;
    float acc[8][8] = {};
    for (int w0 = 0; w0 < W; w0 += 16) {
        __syncthreads();
#pragma unroll
        for (int p = 0; p < 8; ++p) {
            int r = sr0 + 16 * p;
            As[sc][r] = Qb[(size_t)(i0 + r) * W + w0 + sc];
            Bs[sc][r] = Kb[(size_t)(j0 + r) * W + w0 + sc];
        }
        __syncthreads();
#pragma unroll
        for (int kk = 0; kk < 16; ++kk) {
            float a[8], bb[8];
            *reinterpret_cast<float4*>(&a[0])  = *reinterpret_cast<const float4*>(&As[kk][ty * 8]);
            *reinterpret_cast<float4*>(&a[4])  = *reinterpret_cast<const float4*>(&As[kk][ty * 8 + 4]);
            *reinterpret_cast<float4*>(&bb[0]) = *reinterpret_cast<const float4*>(&Bs[kk][tx * 8]);
            *reinterpret_cast<float4*>(&bb[4]) = *reinterpret_cast<const float4*>(&Bs[kk][tx * 8 + 4]);
#pragma unroll
            for (int m = 0; m < 8; ++m)
#pragma unroll
                for (int n = 0; n < 8; ++n)
                    acc[m][n] = fmaf(a[m], bb[n], acc[m][n]);
        }
    }
    float* Cb = attn + (size_t)b * H * H;
#pragma unroll
    for (int m = 0; m < 8; ++m) {
        int row = i0 + ty * 8 + m;
        *reinterpret_cast<float4*>(&Cb[(size_t)row * H + j0 + tx * 8]) =
            make_float4(acc[m][0], acc[m][1], acc[m][2], acc[m][3]);
        *reinterpret_cast<float4*>(&Cb[(size_t)row * H + j0 + tx * 8 + 4]) =
            make_float4(acc[m][4], acc[m][5], acc[m][6], acc[m][7]);
    }
}

// ---------------------------------------------------------------------------
// Kernel 4: row softmax fp32 -> bf16 output
// ---------------------------------------------------------------------------
__global__ __launch_bounds__(256) void softmax_kernel(
    const float* __restrict__ attn, unsigned short* __restrict__ attn_bf)
{
    int gid  = blockIdx.x * 256 + threadIdx.x;
    int row  = gid >> 6;
    int lane = gid & 63;
    const float* rp = attn + (size_t)row * H;
    float4 v0 = *reinterpret_cast<const float4*>(&rp[lane * 8]);
    float4 v1 = *reinterpret_cast<const float4*>(&rp[lane * 8 + 4]);
    float m = fmaxf(fmaxf(fmaxf(v0.x, v0.y), fmaxf(v0.z, v0.w)),
                    fmaxf(fmaxf(v1.x, v1.y), fmaxf(v1.z, v1.w)));
#pragma unroll
    for (int off = 32; off > 0; off >>= 1) m = fmaxf(m, __shfl_xor(m, off, 64));
    v0.x = __expf(v0.x - m); v0.y = __expf(v0.y - m);
    v0.z = __expf(v0.z - m); v0.w = __expf(v0.w - m);
    v1.x = __expf(v1.x - m); v1.y = __expf(v1.y - m);
    v1.z = __expf(v1.z - m); v1.w = __expf(v1.w - m);
    float s = v0.x + v0.y + v0.z + v0.w + v1.x + v1.y + v1.z + v1.w;
#pragma unroll
    for (int off = 32; off > 0; off >>= 1) s += __shfl_xor(s, off, 64);
    float inv = 1.0f / s;
    unsigned short* bp = attn_bf + (size_t)row * H + lane * 8;
    ushort4 o0, o1;
    o0.x = f2bf(v0.x * inv); o0.y = f2bf(v0.y * inv);
    o0.z = f2bf(v0.z * inv); o0.w = f2bf(v0.w * inv);
    o1.x = f2bf(v1.x * inv); o1.y = f2bf(v1.y * inv);
    o1.z = f2bf(v1.z * inv); o1.w = f2bf(v1.w * inv);
    *reinterpret_cast<ushort4*>(bp)     = o0;
    *reinterpret_cast<ushort4*>(bp + 4) = o1;
}

// ---------------------------------------------------------------------------
// Kernel 5: PV GEMM on MFMA. Per batch b: out[i, n=(c,w)] = attn[i,j] vt[n,j].
// 128x128 tile, BK=64, 4 waves (2x2 of 64x64), mfma_f32_16x16x32_bf16.
// global_load_lds (16B) staging, pre-swizzled source + XOR-swizzled ds_read.
// ---------------------------------------------------------------------------
__global__ __launch_bounds__(256, 2) void pv_mfma_kernel(
    const unsigned short* __restrict__ attn_bf,   // [B][H][H] bf16
    const unsigned short* __restrict__ vt,        // [B][C][W][H] bf16
    const float* __restrict__ bv, float* __restrict__ out)
{
    __shared__ char Ash[2][128 * 128];   // 128 rows x 64 bf16 (128B/row) per buf
    __shared__ char Bsh[2][128 * 128];

    int b  = blockIdx.z;
    int i0 = blockIdx.y * 128;
    int n0 = blockIdx.x * 128;           // c = n0>>9, w0 = n0&511
    int tid  = threadIdx.x;
    int lane = tid & 63, wv = tid >> 6;
    int wm = wv >> 1, wn = wv & 1;

    const char* Abase = (const char*)(attn_bf + (size_t)b * H * H);            // row pitch 1024B
    const char* Bbase = (const char*)(vt + (size_t)b * C * HW + (size_t)n0 * H); // row pitch 1024B

    int rsub = lane >> 3;        // 0..7 (row within 8-row chunk)
    int slot = lane & 7;         // 16B slot within 128B row
    int swsl = (slot ^ rsub) << 4;

    f32x4 acc[4][4] = {};

#define STAGE(buf, kt)                                                                   \
    {                                                                                    \
        int koff = (kt) * 128;                                                           \
        _Pragma("unroll")                                                                \
        for (int qq = 0; qq < 4; ++qq) {                                                 \
            int chunk = wv * 4 + qq;                                                     \
            int r = chunk * 8 + rsub;                                                    \
            __builtin_amdgcn_global_load_lds(                                            \
                (const __attribute__((address_space(1))) unsigned int*)                  \
                    (Abase + (size_t)(i0 + r) * 1024 + koff + swsl),                     \
                (__attribute__((address_space(3))) unsigned int*)(Ash[buf] + chunk * 1024), \
                16, 0, 0);                                                               \
            __builtin_amdgcn_global_load_lds(                                            \
                (const __attribute__((address_space(1))) unsigned int*)                  \
                    (Bbase + (size_t)r * 1024 + koff + swsl),                            \
                (__attribute__((address_space(3))) unsigned int*)(Bsh[buf] + chunk * 1024), \
                16, 0, 0);                                                               \
        }                                                                                \
    }

    STAGE(0, 0);
    int cur = 0;
    for (int kt = 0; kt < 8; ++kt) {
        __syncthreads();                 // drains vmcnt: buf[cur] ready; prev reads done
        if (kt + 1 < 8) STAGE(cur ^ 1, kt + 1);

        const char* Ab = Ash[cur];
        const char* Bb = Bsh[cur];
        bf16x8 af[4][2], bf[4][2];
#pragma unroll
        for (int m = 0; m < 4; ++m) {
            int row = wm * 64 + m * 16 + (lane & 15);
            int base = row * 128 + ((lane >> 4) << 4);
            int sw = (row & 7) << 4;
            af[m][0] = *reinterpret_cast<const bf16x8*>(Ab + ((base)      ^ sw));
            af[m][1] = *reinterpret_cast<const bf16x8*>(Ab + ((base + 64) ^ sw));
        }
#pragma unroll
        for (int n = 0; n < 4; ++n) {
            int row = wn * 64 + n * 16 + (lane & 15);
            int base = row * 128 + ((lane >> 4) << 4);
            int sw = (row & 7) << 4;
            bf[n][0] = *reinterpret_cast<const bf16x8*>(Bb + ((base)      ^ sw));
            bf[n][1] = *reinterpret_cast<const bf16x8*>(Bb + ((base + 64) ^ sw));
        }
#pragma unroll
        for (int ks = 0; ks < 2; ++ks)
#pragma unroll
            for (int m = 0; m < 4; ++m)
#pragma unroll
                for (int n = 0; n < 4; ++n)
                    acc[m][n] = __builtin_amdgcn_mfma_f32_16x16x32_bf16(
                        af[m][ks], bf[n][ks], acc[m][n], 0, 0, 0);
        cur ^= 1;
    }
#undef STAGE

    int cc = n0 >> 9;
    int w0 = n0 & 511;
    float bias = bv[cc];
    float* outb = out + ((size_t)(b * C + cc)) * HW;
#pragma unroll
    for (int m = 0; m < 4; ++m) {
        int i = i0 + wm * 64 + m * 16 + ((lane >> 4) << 2);
#pragma unroll
        for (int n = 0; n < 4; ++n) {
            int w = w0 + wn * 64 + n * 16 + (lane & 15);
#pragma unroll
            for (int r = 0; r < 4; ++r)
                outb[(size_t)(i + r) * W + w] = acc[m][n][r] + bias;
        }
    }
}

extern "C" void kernel_launch(void* const* d_in, const int* in_sizes, int n_in,
                              void* d_out, int out_size, void* d_ws, size_t ws_size,
                              hipStream_t stream) {
    const float* x  = (const float*)d_in[0];
    const float* Wq = (const float*)d_in[1];
    const float* bq = (const float*)d_in[2];
    const float* Wk = (const float*)d_in[3];
    const float* bk = (const float*)d_in[4];
    const float* Wv = (const float*)d_in[5];
    const float* bv = (const float*)d_in[6];
    float* out = (float*)d_out;

    // workspace: q, k fp32 | attn fp32 | attn bf16 | vt bf16  (~126 MB)
    float* q = (float*)d_ws;
    float* k = q + (size_t)B * HW;
    float* attnf = k + (size_t)B * HW;
    unsigned short* attnb = (unsigned short*)(attnf + (size_t)B * H * H);
    unsigned short* vtb = attnb + (size_t)B * H * H;
    // v bf16 [b][c][j][w] parked in d_out (67 MB of its 134 MB), dead before PV writes.
    unsigned short* v = (unsigned short*)d_out;

    qkv_kernel<<<B * HW / 4 / 256, 256, 0, stream>>>(x, Wq, bq, Wk, bk, Wv, q, k, v);
    transpose_kernel<<<dim3(64, B * C), 256, 0, stream>>>(v, vtb);
    qk_gemm_kernel<<<dim3(H / 128, H / 128, B), 256, 0, stream>>>(q, k, attnf);
    softmax_kernel<<<(B * H * 64) / 256, 256, 0, stream>>>(attnf, attnb);
    pv_mfma_kernel<<<dim3(32, 4, B), 256, 0, stream>>>(attnb, vtb, bv, out);
}

// Round 3
// 325.349 us; speedup vs baseline: 2.4536x; 1.1628x over previous
//
#include <hip/hip_runtime.h>

constexpr int B = 16, C = 8, H = 512, W = 512;
constexpr int HW = H * W;

typedef short bf16x8 __attribute__((ext_vector_type(8)));
typedef float f32x4 __attribute__((ext_vector_type(4)));

__device__ __forceinline__ unsigned short f2bf(float f) {
    union { float f; unsigned u; } v; v.f = f;
    unsigned r = (v.u + 0x7FFFu + ((v.u >> 16) & 1u)) >> 16;
    return (unsigned short)r;
}
__device__ __forceinline__ float bf2f(unsigned short u) {
    union { unsigned u; float f; } v; v.u = (unsigned)u << 16;
    return v.f;
}
__device__ __forceinline__ void split1(float a, unsigned short& h, unsigned short& l) {
    h = f2bf(a);
    l = f2bf(a - bf2f(h));
}

// ---------------------------------------------------------------------------
// Kernel 1: fused q/k/v 1x1 convs + v transpose.
// Per block: one 64x64 (j,w) tile of one batch. Writes q,k as split-bf16
// planes (hi/lo) and v transposed to vt[b][c][w][j] (bf16, no bias: softmax
// rows sum to 1 so bv is added once in the PV epilogue).
// ---------------------------------------------------------------------------
__global__ __launch_bounds__(256) void qkv_fused_kernel(
    const float* __restrict__ x, const float* __restrict__ Wq, const float* __restrict__ bq,
    const float* __restrict__ Wk, const float* __restrict__ bk, const float* __restrict__ Wv,
    unsigned short* __restrict__ qh, unsigned short* __restrict__ ql,
    unsigned short* __restrict__ kh, unsigned short* __restrict__ kl,
    unsigned short* __restrict__ vt)
{
    __shared__ int ldsv[4][64][65];   // channel-pair packed (lo16=ch even, hi16=ch odd)
    int b  = blockIdx.y;
    int j0 = (blockIdx.x >> 3) * 64;
    int w0 = (blockIdx.x & 7) * 64;
    const float* xb = x + (size_t)b * C * HW;
    int t  = threadIdx.x;
    int jr = t >> 4, c4 = (t & 15) * 4;

    float wq[8], wk[8], wv[8][8];
#pragma unroll
    for (int cc = 0; cc < 8; ++cc) {
        wq[cc] = Wq[cc]; wk[cc] = Wk[cc];
#pragma unroll
        for (int c = 0; c < 8; ++c) wv[c][cc] = Wv[c * 8 + cc];
    }
    float bq0 = bq[0], bk0 = bk[0];

#pragma unroll
    for (int rr = 0; rr < 4; ++rr) {
        int j = jr + rr * 16;
        size_t prow = (size_t)(j0 + j) * W + w0 + c4;
        float4 aq = make_float4(bq0, bq0, bq0, bq0);
        float4 ak = make_float4(bk0, bk0, bk0, bk0);
        float vacc[8][4] = {};
#pragma unroll
        for (int cc = 0; cc < 8; ++cc) {
            float4 xv = *reinterpret_cast<const float4*>(xb + (size_t)cc * HW + prow);
            aq.x = fmaf(wq[cc], xv.x, aq.x); aq.y = fmaf(wq[cc], xv.y, aq.y);
            aq.z = fmaf(wq[cc], xv.z, aq.z); aq.w = fmaf(wq[cc], xv.w, aq.w);
            ak.x = fmaf(wk[cc], xv.x, ak.x); ak.y = fmaf(wk[cc], xv.y, ak.y);
            ak.z = fmaf(wk[cc], xv.z, ak.z); ak.w = fmaf(wk[cc], xv.w, ak.w);
#pragma unroll
            for (int c = 0; c < 8; ++c) {
                vacc[c][0] = fmaf(wv[c][cc], xv.x, vacc[c][0]);
                vacc[c][1] = fmaf(wv[c][cc], xv.y, vacc[c][1]);
                vacc[c][2] = fmaf(wv[c][cc], xv.z, vacc[c][2]);
                vacc[c][3] = fmaf(wv[c][cc], xv.w, vacc[c][3]);
            }
        }
        size_t qoff = (size_t)b * HW + prow;
        ushort4 h4, l4;
        split1(aq.x, h4.x, l4.x); split1(aq.y, h4.y, l4.y);
        split1(aq.z, h4.z, l4.z); split1(aq.w, h4.w, l4.w);
        *reinterpret_cast<ushort4*>(qh + qoff) = h4;
        *reinterpret_cast<ushort4*>(ql + qoff) = l4;
        split1(ak.x, h4.x, l4.x); split1(ak.y, h4.y, l4.y);
        split1(ak.z, h4.z, l4.z); split1(ak.w, h4.w, l4.w);
        *reinterpret_cast<ushort4*>(kh + qoff) = h4;
        *reinterpret_cast<ushort4*>(kl + qoff) = l4;
#pragma unroll
        for (int cp = 0; cp < 4; ++cp)
#pragma unroll
            for (int i = 0; i < 4; ++i)
                ldsv[cp][j][c4 + i] =
                    (unsigned)f2bf(vacc[2 * cp][i]) | ((unsigned)f2bf(vacc[2 * cp + 1][i]) << 16);
    }
    __syncthreads();
#pragma unroll
    for (int cp = 0; cp < 4; ++cp) {
#pragma unroll
        for (int rr = 0; rr < 4; ++rr) {
            int w = jr + rr * 16;
            int d0 = ldsv[cp][c4 + 0][w];
            int d1 = ldsv[cp][c4 + 1][w];
            int d2 = ldsv[cp][c4 + 2][w];
            int d3 = ldsv[cp][c4 + 3][w];
            ushort4 e, o;
            e.x = (unsigned short)d0; o.x = (unsigned short)(d0 >> 16);
            e.y = (unsigned short)d1; o.y = (unsigned short)(d1 >> 16);
            e.z = (unsigned short)d2; o.z = (unsigned short)(d2 >> 16);
            e.w = (unsigned short)d3; o.w = (unsigned short)(d3 >> 16);
            size_t voff = (size_t)(w0 + w) * H + j0 + c4;
            *reinterpret_cast<ushort4*>(vt + ((size_t)(b * 8 + 2 * cp))     * HW + voff) = e;
            *reinterpret_cast<ushort4*>(vt + ((size_t)(b * 8 + 2 * cp + 1)) * HW + voff) = o;
        }
    }
}

// ---------------------------------------------------------------------------
// Kernel 2: attn[b,i,j] = q[b,i,:]·k[b,j,:] via split-bf16 MFMA (3 terms:
// qh·kh + qh·kl + ql·kh; logits ~fp32 accurate). 128x128 tile, BK=32,
// hi/lo interleaved as 8x16B slots per 128B LDS row, XOR(row&7) swizzle.
// ---------------------------------------------------------------------------
__global__ __launch_bounds__(256, 2) void qk_mfma_kernel(
    const unsigned short* __restrict__ qh_, const unsigned short* __restrict__ ql_,
    const unsigned short* __restrict__ kh_, const unsigned short* __restrict__ kl_,
    float* __restrict__ attn)
{
    __shared__ char Ash[2][16384];
    __shared__ char Bsh[2][16384];
    int b  = blockIdx.z;
    int i0 = blockIdx.y * 128;
    int j0 = blockIdx.x * 128;
    int tid  = threadIdx.x;
    int lane = tid & 63, wv4 = tid >> 6;
    int wm = wv4 >> 1, wn = wv4 & 1;

    const char* qhB = (const char*)qh_ + (size_t)b * HW * 2;
    const char* qlB = (const char*)ql_ + (size_t)b * HW * 2;
    const char* khB = (const char*)kh_ + (size_t)b * HW * 2;
    const char* klB = (const char*)kl_ + (size_t)b * HW * 2;

    // staging decomposition (dest = uniform base + lane*16):
    //   row = pass*32 + wv4*8 + (lane>>3), phys slot = lane&7,
    //   logical slot ls = (lane&7) ^ (lane>>3);  h = ls&1, s = ls>>1
    int ls  = (lane & 7) ^ (lane >> 3);
    int hsel = ls & 1, ssel = ls >> 1;

    f32x4 acc[4][4] = {};

#define STAGE(buf, kt)                                                                    \
    {                                                                                     \
        _Pragma("unroll")                                                                 \
        for (int pass = 0; pass < 4; ++pass) {                                            \
            int row = pass * 32 + wv4 * 8 + (lane >> 3);                                  \
            const char* sA = (hsel ? qlB : qhB) + (size_t)(i0 + row) * 1024 + (kt) * 64 + ssel * 16; \
            const char* sB = (hsel ? klB : khB) + (size_t)(j0 + row) * 1024 + (kt) * 64 + ssel * 16; \
            __builtin_amdgcn_global_load_lds(                                             \
                (const __attribute__((address_space(1))) unsigned int*)sA,                \
                (__attribute__((address_space(3))) unsigned int*)(Ash[buf] + pass * 4096 + wv4 * 1024), \
                16, 0, 0);                                                                \
            __builtin_amdgcn_global_load_lds(                                             \
                (const __attribute__((address_space(1))) unsigned int*)sB,                \
                (__attribute__((address_space(3))) unsigned int*)(Bsh[buf] + pass * 4096 + wv4 * 1024), \
                16, 0, 0);                                                                \
        }                                                                                 \
    }

    STAGE(0, 0);
    int cur = 0;
    for (int kt = 0; kt < 16; ++kt) {
        __syncthreads();                       // buf[cur] staged & prior reads done
        if (kt + 1 < 16) STAGE(cur ^ 1, kt + 1);

        const char* Ab = Ash[cur];
        const char* Bb = Bsh[cur];
        bf16x8 ah[4], al[4], bh[4], bl[4];
        int sr = lane >> 4;                    // k-chunk 0..3
#pragma unroll
        for (int m = 0; m < 4; ++m) {
            int row = wm * 64 + m * 16 + (lane & 15);
            int sw = row & 7;
            ah[m] = *reinterpret_cast<const bf16x8*>(Ab + row * 128 + ((2 * sr)     ^ sw) * 16);
            al[m] = *reinterpret_cast<const bf16x8*>(Ab + row * 128 + ((2 * sr + 1) ^ sw) * 16);
        }
#pragma unroll
        for (int n = 0; n < 4; ++n) {
            int row = wn * 64 + n * 16 + (lane & 15);
            int sw = row & 7;
            bh[n] = *reinterpret_cast<const bf16x8*>(Bb + row * 128 + ((2 * sr)     ^ sw) * 16);
            bl[n] = *reinterpret_cast<const bf16x8*>(Bb + row * 128 + ((2 * sr + 1) ^ sw) * 16);
        }
#pragma unroll
        for (int m = 0; m < 4; ++m)
#pragma unroll
            for (int n = 0; n < 4; ++n) {
                acc[m][n] = __builtin_amdgcn_mfma_f32_16x16x32_bf16(ah[m], bh[n], acc[m][n], 0, 0, 0);
                acc[m][n] = __builtin_amdgcn_mfma_f32_16x16x32_bf16(ah[m], bl[n], acc[m][n], 0, 0, 0);
                acc[m][n] = __builtin_amdgcn_mfma_f32_16x16x32_bf16(al[m], bh[n], acc[m][n], 0, 0, 0);
            }
        cur ^= 1;
    }
#undef STAGE

    float* Cb = attn + (size_t)b * H * H;
#pragma unroll
    for (int m = 0; m < 4; ++m) {
        int i = i0 + wm * 64 + m * 16 + ((lane >> 4) << 2);
#pragma unroll
        for (int n = 0; n < 4; ++n) {
            int j = j0 + wn * 64 + n * 16 + (lane & 15);
#pragma unroll
            for (int r = 0; r < 4; ++r)
                Cb[(size_t)(i + r) * H + j] = acc[m][n][r];
        }
    }
}

// ---------------------------------------------------------------------------
// Kernel 3: row softmax fp32 -> bf16 output
// ---------------------------------------------------------------------------
__global__ __launch_bounds__(256) void softmax_kernel(
    const float* __restrict__ attn, unsigned short* __restrict__ attn_bf)
{
    int gid  = blockIdx.x * 256 + threadIdx.x;
    int row  = gid >> 6;
    int lane = gid & 63;
    const float* rp = attn + (size_t)row * H;
    float4 v0 = *reinterpret_cast<const float4*>(&rp[lane * 8]);
    float4 v1 = *reinterpret_cast<const float4*>(&rp[lane * 8 + 4]);
    float m = fmaxf(fmaxf(fmaxf(v0.x, v0.y), fmaxf(v0.z, v0.w)),
                    fmaxf(fmaxf(v1.x, v1.y), fmaxf(v1.z, v1.w)));
#pragma unroll
    for (int off = 32; off > 0; off >>= 1) m = fmaxf(m, __shfl_xor(m, off, 64));
    v0.x = __expf(v0.x - m); v0.y = __expf(v0.y - m);
    v0.z = __expf(v0.z - m); v0.w = __expf(v0.w - m);
    v1.x = __expf(v1.x - m); v1.y = __expf(v1.y - m);
    v1.z = __expf(v1.z - m); v1.w = __expf(v1.w - m);
    float s = v0.x + v0.y + v0.z + v0.w + v1.x + v1.y + v1.z + v1.w;
#pragma unroll
    for (int off = 32; off > 0; off >>= 1) s += __shfl_xor(s, off, 64);
    float inv = 1.0f / s;
    unsigned short* bp = attn_bf + (size_t)row * H + lane * 8;
    ushort4 o0, o1;
    o0.x = f2bf(v0.x * inv); o0.y = f2bf(v0.y * inv);
    o0.z = f2bf(v0.z * inv); o0.w = f2bf(v0.w * inv);
    o1.x = f2bf(v1.x * inv); o1.y = f2bf(v1.y * inv);
    o1.z = f2bf(v1.z * inv); o1.w = f2bf(v1.w * inv);
    *reinterpret_cast<ushort4*>(bp)     = o0;
    *reinterpret_cast<ushort4*>(bp + 4) = o1;
}

// ---------------------------------------------------------------------------
// Kernel 4: PV GEMM on MFMA (unchanged from round 2).
// ---------------------------------------------------------------------------
__global__ __launch_bounds__(256, 2) void pv_mfma_kernel(
    const unsigned short* __restrict__ attn_bf,   // [B][H][H] bf16
    const unsigned short* __restrict__ vt,        // [B][C][W][H] bf16
    const float* __restrict__ bv, float* __restrict__ out)
{
    __shared__ char Ash[2][128 * 128];
    __shared__ char Bsh[2][128 * 128];

    int b  = blockIdx.z;
    int i0 = blockIdx.y * 128;
    int n0 = blockIdx.x * 128;
    int tid  = threadIdx.x;
    int lane = tid & 63, wv = tid >> 6;
    int wm = wv >> 1, wn = wv & 1;

    const char* Abase = (const char*)(attn_bf + (size_t)b * H * H);
    const char* Bbase = (const char*)(vt + (size_t)b * C * HW + (size_t)n0 * H);

    int rsub = lane >> 3;
    int slot = lane & 7;
    int swsl = (slot ^ rsub) << 4;

    f32x4 acc[4][4] = {};

#define STAGE(buf, kt)                                                                   \
    {                                                                                    \
        int koff = (kt) * 128;                                                           \
        _Pragma("unroll")                                                                \
        for (int qq = 0; qq < 4; ++qq) {                                                 \
            int chunk = wv * 4 + qq;                                                     \
            int r = chunk * 8 + rsub;                                                    \
            __builtin_amdgcn_global_load_lds(                                            \
                (const __attribute__((address_space(1))) unsigned int*)                  \
                    (Abase + (size_t)(i0 + r) * 1024 + koff + swsl),                     \
                (__attribute__((address_space(3))) unsigned int*)(Ash[buf] + chunk * 1024), \
                16, 0, 0);                                                               \
            __builtin_amdgcn_global_load_lds(                                            \
                (const __attribute__((address_space(1))) unsigned int*)                  \
                    (Bbase + (size_t)r * 1024 + koff + swsl),                            \
                (__attribute__((address_space(3))) unsigned int*)(Bsh[buf] + chunk * 1024), \
                16, 0, 0);                                                               \
        }                                                                                \
    }

    STAGE(0, 0);
    int cur = 0;
    for (int kt = 0; kt < 8; ++kt) {
        __syncthreads();
        if (kt + 1 < 8) STAGE(cur ^ 1, kt + 1);

        const char* Ab = Ash[cur];
        const char* Bb = Bsh[cur];
        bf16x8 af[4][2], bf[4][2];
#pragma unroll
        for (int m = 0; m < 4; ++m) {
            int row = wm * 64 + m * 16 + (lane & 15);
            int base = row * 128 + ((lane >> 4) << 4);
            int sw = (row & 7) << 4;
            af[m][0] = *reinterpret_cast<const bf16x8*>(Ab + ((base)      ^ sw));
            af[m][1] = *reinterpret_cast<const bf16x8*>(Ab + ((base + 64) ^ sw));
        }
#pragma unroll
        for (int n = 0; n < 4; ++n) {
            int row = wn * 64 + n * 16 + (lane & 15);
            int base = row * 128 + ((lane >> 4) << 4);
            int sw = (row & 7) << 4;
            bf[n][0] = *reinterpret_cast<const bf16x8*>(Bb + ((base)      ^ sw));
            bf[n][1] = *reinterpret_cast<const bf16x8*>(Bb + ((base + 64) ^ sw));
        }
#pragma unroll
        for (int ks = 0; ks < 2; ++ks)
#pragma unroll
            for (int m = 0; m < 4; ++m)
#pragma unroll
                for (int n = 0; n < 4; ++n)
                    acc[m][n] = __builtin_amdgcn_mfma_f32_16x16x32_bf16(
                        af[m][ks], bf[n][ks], acc[m][n], 0, 0, 0);
        cur ^= 1;
    }
#undef STAGE

    int cc = n0 >> 9;
    int w0 = n0 & 511;
    float bias = bv[cc];
    float* outb = out + ((size_t)(b * C + cc)) * HW;
#pragma unroll
    for (int m = 0; m < 4; ++m) {
        int i = i0 + wm * 64 + m * 16 + ((lane >> 4) << 2);
#pragma unroll
        for (int n = 0; n < 4; ++n) {
            int w = w0 + wn * 64 + n * 16 + (lane & 15);
#pragma unroll
            for (int r = 0; r < 4; ++r)
                outb[(size_t)(i + r) * W + w] = acc[m][n][r] + bias;
        }
    }
}

extern "C" void kernel_launch(void* const* d_in, const int* in_sizes, int n_in,
                              void* d_out, int out_size, void* d_ws, size_t ws_size,
                              hipStream_t stream) {
    const float* x  = (const float*)d_in[0];
    const float* Wq = (const float*)d_in[1];
    const float* bq = (const float*)d_in[2];
    const float* Wk = (const float*)d_in[3];
    const float* bk = (const float*)d_in[4];
    const float* Wv = (const float*)d_in[5];
    const float* bv = (const float*)d_in[6];
    float* out = (float*)d_out;

    // workspace: qh|ql|kh|kl bf16 (33.6MB) | attn fp32 (16.8) | attn bf16 (8.4) | vt bf16 (67)
    unsigned short* qh = (unsigned short*)d_ws;
    unsigned short* ql = qh + (size_t)B * HW;
    unsigned short* kh = ql + (size_t)B * HW;
    unsigned short* kl = kh + (size_t)B * HW;
    float* attnf = (float*)(kl + (size_t)B * HW);
    unsigned short* attnb = (unsigned short*)(attnf + (size_t)B * H * H);
    unsigned short* vtb = attnb + (size_t)B * H * H;

    qkv_fused_kernel<<<dim3(64, B), 256, 0, stream>>>(x, Wq, bq, Wk, bk, Wv, qh, ql, kh, kl, vtb);
    qk_mfma_kernel<<<dim3(4, 4, B), 256, 0, stream>>>(qh, ql, kh, kl, attnf);
    softmax_kernel<<<(B * H * 64) / 256, 256, 0, stream>>>(attnf, attnb);
    pv_mfma_kernel<<<dim3(32, 4, B), 256, 0, stream>>>(attnb, vtb, bv, out);
}

// Round 4
// 323.170 us; speedup vs baseline: 2.4702x; 1.0067x over previous
//
#include <hip/hip_runtime.h>

constexpr int B = 16, C = 8, H = 512, W = 512;
constexpr int HW = H * W;

typedef short bf16x8 __attribute__((ext_vector_type(8)));
typedef float f32x4 __attribute__((ext_vector_type(4)));

__device__ __forceinline__ unsigned short f2bf(float f) {
    union { float f; unsigned u; } v; v.f = f;
    unsigned r = (v.u + 0x7FFFu + ((v.u >> 16) & 1u)) >> 16;
    return (unsigned short)r;
}
__device__ __forceinline__ float bf2f(unsigned short u) {
    union { unsigned u; float f; } v; v.u = (unsigned)u << 16;
    return v.f;
}
__device__ __forceinline__ void split1(float a, unsigned short& h, unsigned short& l) {
    h = f2bf(a);
    l = f2bf(a - bf2f(h));
}

// ---------------------------------------------------------------------------
// Kernel 1: fused q/k/v 1x1 convs + v transpose. (unchanged from round 3)
// ---------------------------------------------------------------------------
__global__ __launch_bounds__(256) void qkv_fused_kernel(
    const float* __restrict__ x, const float* __restrict__ Wq, const float* __restrict__ bq,
    const float* __restrict__ Wk, const float* __restrict__ bk, const float* __restrict__ Wv,
    unsigned short* __restrict__ qh, unsigned short* __restrict__ ql,
    unsigned short* __restrict__ kh, unsigned short* __restrict__ kl,
    unsigned short* __restrict__ vt)
{
    __shared__ int ldsv[4][64][65];
    int b  = blockIdx.y;
    int j0 = (blockIdx.x >> 3) * 64;
    int w0 = (blockIdx.x & 7) * 64;
    const float* xb = x + (size_t)b * C * HW;
    int t  = threadIdx.x;
    int jr = t >> 4, c4 = (t & 15) * 4;

    float wq[8], wk[8], wv[8][8];
#pragma unroll
    for (int cc = 0; cc < 8; ++cc) {
        wq[cc] = Wq[cc]; wk[cc] = Wk[cc];
#pragma unroll
        for (int c = 0; c < 8; ++c) wv[c][cc] = Wv[c * 8 + cc];
    }
    float bq0 = bq[0], bk0 = bk[0];

#pragma unroll
    for (int rr = 0; rr < 4; ++rr) {
        int j = jr + rr * 16;
        size_t prow = (size_t)(j0 + j) * W + w0 + c4;
        float4 aq = make_float4(bq0, bq0, bq0, bq0);
        float4 ak = make_float4(bk0, bk0, bk0, bk0);
        float vacc[8][4] = {};
#pragma unroll
        for (int cc = 0; cc < 8; ++cc) {
            float4 xv = *reinterpret_cast<const float4*>(xb + (size_t)cc * HW + prow);
            aq.x = fmaf(wq[cc], xv.x, aq.x); aq.y = fmaf(wq[cc], xv.y, aq.y);
            aq.z = fmaf(wq[cc], xv.z, aq.z); aq.w = fmaf(wq[cc], xv.w, aq.w);
            ak.x = fmaf(wk[cc], xv.x, ak.x); ak.y = fmaf(wk[cc], xv.y, ak.y);
            ak.z = fmaf(wk[cc], xv.z, ak.z); ak.w = fmaf(wk[cc], xv.w, ak.w);
#pragma unroll
            for (int c = 0; c < 8; ++c) {
                vacc[c][0] = fmaf(wv[c][cc], xv.x, vacc[c][0]);
                vacc[c][1] = fmaf(wv[c][cc], xv.y, vacc[c][1]);
                vacc[c][2] = fmaf(wv[c][cc], xv.z, vacc[c][2]);
                vacc[c][3] = fmaf(wv[c][cc], xv.w, vacc[c][3]);
            }
        }
        size_t qoff = (size_t)b * HW + prow;
        ushort4 h4, l4;
        split1(aq.x, h4.x, l4.x); split1(aq.y, h4.y, l4.y);
        split1(aq.z, h4.z, l4.z); split1(aq.w, h4.w, l4.w);
        *reinterpret_cast<ushort4*>(qh + qoff) = h4;
        *reinterpret_cast<ushort4*>(ql + qoff) = l4;
        split1(ak.x, h4.x, l4.x); split1(ak.y, h4.y, l4.y);
        split1(ak.z, h4.z, l4.z); split1(ak.w, h4.w, l4.w);
        *reinterpret_cast<ushort4*>(kh + qoff) = h4;
        *reinterpret_cast<ushort4*>(kl + qoff) = l4;
#pragma unroll
        for (int cp = 0; cp < 4; ++cp)
#pragma unroll
            for (int i = 0; i < 4; ++i)
                ldsv[cp][j][c4 + i] =
                    (unsigned)f2bf(vacc[2 * cp][i]) | ((unsigned)f2bf(vacc[2 * cp + 1][i]) << 16);
    }
    __syncthreads();
#pragma unroll
    for (int cp = 0; cp < 4; ++cp) {
#pragma unroll
        for (int rr = 0; rr < 4; ++rr) {
            int w = jr + rr * 16;
            int d0 = ldsv[cp][c4 + 0][w];
            int d1 = ldsv[cp][c4 + 1][w];
            int d2 = ldsv[cp][c4 + 2][w];
            int d3 = ldsv[cp][c4 + 3][w];
            ushort4 e, o;
            e.x = (unsigned short)d0; o.x = (unsigned short)(d0 >> 16);
            e.y = (unsigned short)d1; o.y = (unsigned short)(d1 >> 16);
            e.z = (unsigned short)d2; o.z = (unsigned short)(d2 >> 16);
            e.w = (unsigned short)d3; o.w = (unsigned short)(d3 >> 16);
            size_t voff = (size_t)(w0 + w) * H + j0 + c4;
            *reinterpret_cast<ushort4*>(vt + ((size_t)(b * 8 + 2 * cp))     * HW + voff) = e;
            *reinterpret_cast<ushort4*>(vt + ((size_t)(b * 8 + 2 * cp + 1)) * HW + voff) = o;
        }
    }
}

// ---------------------------------------------------------------------------
// Kernel 2: attn logits via split-bf16 MFMA (3 terms). 128x128, BK=32.
// Round-4 change: flattened grid + bijective XCD swizzle (j-tile fastest).
// ---------------------------------------------------------------------------
__global__ __launch_bounds__(256, 2) void qk_mfma_kernel(
    const unsigned short* __restrict__ qh_, const unsigned short* __restrict__ ql_,
    const unsigned short* __restrict__ kh_, const unsigned short* __restrict__ kl_,
    float* __restrict__ attn)
{
    __shared__ char Ash[2][16384];
    __shared__ char Bsh[2][16384];
    int lin = blockIdx.x;                      // 0..255 ; 256 % 8 == 0 -> bijective
    int swz = (lin & 7) * 32 + (lin >> 3);
    int b   = swz >> 4;
    int rr_ = swz & 15;
    int i0 = (rr_ >> 2) * 128;
    int j0 = (rr_ & 3) * 128;
    int tid  = threadIdx.x;
    int lane = tid & 63, wv4 = tid >> 6;
    int wm = wv4 >> 1, wn = wv4 & 1;

    const char* qhB = (const char*)qh_ + (size_t)b * HW * 2;
    const char* qlB = (const char*)ql_ + (size_t)b * HW * 2;
    const char* khB = (const char*)kh_ + (size_t)b * HW * 2;
    const char* klB = (const char*)kl_ + (size_t)b * HW * 2;

    int ls  = (lane & 7) ^ (lane >> 3);
    int hsel = ls & 1, ssel = ls >> 1;

    f32x4 acc[4][4] = {};

#define STAGE(buf, kt)                                                                    \
    {                                                                                     \
        _Pragma("unroll")                                                                 \
        for (int pass = 0; pass < 4; ++pass) {                                            \
            int row = pass * 32 + wv4 * 8 + (lane >> 3);                                  \
            const char* sA = (hsel ? qlB : qhB) + (size_t)(i0 + row) * 1024 + (kt) * 64 + ssel * 16; \
            const char* sB = (hsel ? klB : khB) + (size_t)(j0 + row) * 1024 + (kt) * 64 + ssel * 16; \
            __builtin_amdgcn_global_load_lds(                                             \
                (const __attribute__((address_space(1))) unsigned int*)sA,                \
                (__attribute__((address_space(3))) unsigned int*)(Ash[buf] + pass * 4096 + wv4 * 1024), \
                16, 0, 0);                                                                \
            __builtin_amdgcn_global_load_lds(                                             \
                (const __attribute__((address_space(1))) unsigned int*)sB,                \
                (__attribute__((address_space(3))) unsigned int*)(Bsh[buf] + pass * 4096 + wv4 * 1024), \
                16, 0, 0);                                                                \
        }                                                                                 \
    }

    STAGE(0, 0);
    int cur = 0;
    for (int kt = 0; kt < 16; ++kt) {
        __syncthreads();
        if (kt + 1 < 16) STAGE(cur ^ 1, kt + 1);

        const char* Ab = Ash[cur];
        const char* Bb = Bsh[cur];
        bf16x8 ah[4], al[4], bh[4], bl[4];
        int sr = lane >> 4;
#pragma unroll
        for (int m = 0; m < 4; ++m) {
            int row = wm * 64 + m * 16 + (lane & 15);
            int sw = row & 7;
            ah[m] = *reinterpret_cast<const bf16x8*>(Ab + row * 128 + ((2 * sr)     ^ sw) * 16);
            al[m] = *reinterpret_cast<const bf16x8*>(Ab + row * 128 + ((2 * sr + 1) ^ sw) * 16);
        }
#pragma unroll
        for (int n = 0; n < 4; ++n) {
            int row = wn * 64 + n * 16 + (lane & 15);
            int sw = row & 7;
            bh[n] = *reinterpret_cast<const bf16x8*>(Bb + row * 128 + ((2 * sr)     ^ sw) * 16);
            bl[n] = *reinterpret_cast<const bf16x8*>(Bb + row * 128 + ((2 * sr + 1) ^ sw) * 16);
        }
#pragma unroll
        for (int m = 0; m < 4; ++m)
#pragma unroll
            for (int n = 0; n < 4; ++n) {
                acc[m][n] = __builtin_amdgcn_mfma_f32_16x16x32_bf16(ah[m], bh[n], acc[m][n], 0, 0, 0);
                acc[m][n] = __builtin_amdgcn_mfma_f32_16x16x32_bf16(ah[m], bl[n], acc[m][n], 0, 0, 0);
                acc[m][n] = __builtin_amdgcn_mfma_f32_16x16x32_bf16(al[m], bh[n], acc[m][n], 0, 0, 0);
            }
        cur ^= 1;
    }
#undef STAGE

    float* Cb = attn + (size_t)b * H * H;
#pragma unroll
    for (int m = 0; m < 4; ++m) {
        int i = i0 + wm * 64 + m * 16 + ((lane >> 4) << 2);
#pragma unroll
        for (int n = 0; n < 4; ++n) {
            int j = j0 + wn * 64 + n * 16 + (lane & 15);
#pragma unroll
            for (int r = 0; r < 4; ++r)
                Cb[(size_t)(i + r) * H + j] = acc[m][n][r];
        }
    }
}

// ---------------------------------------------------------------------------
// Kernel 3: row softmax fp32 -> bf16 (unchanged)
// ---------------------------------------------------------------------------
__global__ __launch_bounds__(256) void softmax_kernel(
    const float* __restrict__ attn, unsigned short* __restrict__ attn_bf)
{
    int gid  = blockIdx.x * 256 + threadIdx.x;
    int row  = gid >> 6;
    int lane = gid & 63;
    const float* rp = attn + (size_t)row * H;
    float4 v0 = *reinterpret_cast<const float4*>(&rp[lane * 8]);
    float4 v1 = *reinterpret_cast<const float4*>(&rp[lane * 8 + 4]);
    float m = fmaxf(fmaxf(fmaxf(v0.x, v0.y), fmaxf(v0.z, v0.w)),
                    fmaxf(fmaxf(v1.x, v1.y), fmaxf(v1.z, v1.w)));
#pragma unroll
    for (int off = 32; off > 0; off >>= 1) m = fmaxf(m, __shfl_xor(m, off, 64));
    v0.x = __expf(v0.x - m); v0.y = __expf(v0.y - m);
    v0.z = __expf(v0.z - m); v0.w = __expf(v0.w - m);
    v1.x = __expf(v1.x - m); v1.y = __expf(v1.y - m);
    v1.z = __expf(v1.z - m); v1.w = __expf(v1.w - m);
    float s = v0.x + v0.y + v0.z + v0.w + v1.x + v1.y + v1.z + v1.w;
#pragma unroll
    for (int off = 32; off > 0; off >>= 1) s += __shfl_xor(s, off, 64);
    float inv = 1.0f / s;
    unsigned short* bp = attn_bf + (size_t)row * H + lane * 8;
    ushort4 o0, o1;
    o0.x = f2bf(v0.x * inv); o0.y = f2bf(v0.y * inv);
    o0.z = f2bf(v0.z * inv); o0.w = f2bf(v0.w * inv);
    o1.x = f2bf(v1.x * inv); o1.y = f2bf(v1.y * inv);
    o1.z = f2bf(v1.z * inv); o1.w = f2bf(v1.w * inv);
    *reinterpret_cast<ushort4*>(bp)     = o0;
    *reinterpret_cast<ushort4*>(bp + 4) = o1;
}

// ---------------------------------------------------------------------------
// Kernel 4: PV GEMM. Round-4 changes: BK=32 (m97 config: 32 KB LDS -> 3
// blocks/CU), slot^((row>>1)&3) LDS swizzle for 64B rows, flattened grid
// with bijective XCD swizzle, i-tile fastest (vt-panel L2 reuse).
// ---------------------------------------------------------------------------
__global__ __launch_bounds__(256, 3) void pv_mfma_kernel(
    const unsigned short* __restrict__ attn_bf,   // [B][H][H] bf16
    const unsigned short* __restrict__ vt,        // [B][C][W][H] bf16
    const float* __restrict__ bv, float* __restrict__ out)
{
    __shared__ char Ash[2][8192];    // 128 rows x 32 bf16 (64B/row)
    __shared__ char Bsh[2][8192];

    int lin = blockIdx.x;                      // 0..2047 ; 2048 % 8 == 0
    int swz = (lin & 7) * 256 + (lin >> 3);    // XCD-contiguous chunks of 256
    int b   = swz >> 7;
    int r_  = swz & 127;
    int n0  = (r_ >> 2) * 128;                 // i fastest: 4 i-blocks share vt panel
    int i0  = (r_ & 3) * 128;
    int tid  = threadIdx.x;
    int lane = tid & 63, wv = tid >> 6;
    int wm = wv >> 1, wn = wv & 1;

    const char* Abase = (const char*)(attn_bf + (size_t)b * H * H);                // 1024B rows
    const char* Bbase = (const char*)(vt + (size_t)b * C * HW + (size_t)n0 * H);   // 1024B rows

    int srow  = lane >> 2;                        // row within 16-row chunk
    int sslot = ((lane & 3) ^ ((lane >> 3) & 3)) << 4;  // pre-swizzled source slot

    f32x4 acc[4][4] = {};

#define STAGE(buf, kt)                                                                   \
    {                                                                                    \
        int koff = (kt) * 64;                                                            \
        _Pragma("unroll")                                                                \
        for (int qq = 0; qq < 2; ++qq) {                                                 \
            int chunk = wv * 2 + qq;                                                     \
            int r = chunk * 16 + srow;                                                   \
            __builtin_amdgcn_global_load_lds(                                            \
                (const __attribute__((address_space(1))) unsigned int*)                  \
                    (Abase + (size_t)(i0 + r) * 1024 + koff + sslot),                    \
                (__attribute__((address_space(3))) unsigned int*)(Ash[buf] + chunk * 1024), \
                16, 0, 0);                                                               \
            __builtin_amdgcn_global_load_lds(                                            \
                (const __attribute__((address_space(1))) unsigned int*)                  \
                    (Bbase + (size_t)r * 1024 + koff + sslot),                           \
                (__attribute__((address_space(3))) unsigned int*)(Bsh[buf] + chunk * 1024), \
                16, 0, 0);                                                               \
        }                                                                                \
    }

    STAGE(0, 0);
    int cur = 0;
    for (int kt = 0; kt < 16; ++kt) {
        __syncthreads();
        if (kt + 1 < 16) STAGE(cur ^ 1, kt + 1);

        const char* Ab = Ash[cur];
        const char* Bb = Bsh[cur];
        int kc = lane >> 4;                       // k-chunk 0..3 (8 bf16 each)
        bf16x8 af[4], bf[4];
#pragma unroll
        for (int m = 0; m < 4; ++m) {
            int row = wm * 64 + m * 16 + (lane & 15);
            af[m] = *reinterpret_cast<const bf16x8*>(
                Ab + row * 64 + ((kc ^ ((row >> 1) & 3)) << 4));
        }
#pragma unroll
        for (int n = 0; n < 4; ++n) {
            int row = wn * 64 + n * 16 + (lane & 15);
            bf[n] = *reinterpret_cast<const bf16x8*>(
                Bb + row * 64 + ((kc ^ ((row >> 1) & 3)) << 4));
        }
#pragma unroll
        for (int m = 0; m < 4; ++m)
#pragma unroll
            for (int n = 0; n < 4; ++n)
                acc[m][n] = __builtin_amdgcn_mfma_f32_16x16x32_bf16(
                    af[m], bf[n], acc[m][n], 0, 0, 0);
        cur ^= 1;
    }
#undef STAGE

    int cc = n0 >> 9;
    int w0 = n0 & 511;
    float bias = bv[cc];
    float* outb = out + ((size_t)(b * C + cc)) * HW;
#pragma unroll
    for (int m = 0; m < 4; ++m) {
        int i = i0 + wm * 64 + m * 16 + ((lane >> 4) << 2);
#pragma unroll
        for (int n = 0; n < 4; ++n) {
            int w = w0 + wn * 64 + n * 16 + (lane & 15);
#pragma unroll
            for (int r = 0; r < 4; ++r)
                outb[(size_t)(i + r) * W + w] = acc[m][n][r] + bias;
        }
    }
}

extern "C" void kernel_launch(void* const* d_in, const int* in_sizes, int n_in,
                              void* d_out, int out_size, void* d_ws, size_t ws_size,
                              hipStream_t stream) {
    const float* x  = (const float*)d_in[0];
    const float* Wq = (const float*)d_in[1];
    const float* bq = (const float*)d_in[2];
    const float* Wk = (const float*)d_in[3];
    const float* bk = (const float*)d_in[4];
    const float* Wv = (const float*)d_in[5];
    const float* bv = (const float*)d_in[6];
    float* out = (float*)d_out;

    // workspace: qh|ql|kh|kl bf16 (33.6MB) | attn fp32 (16.8) | attn bf16 (8.4) | vt bf16 (67)
    unsigned short* qh = (unsigned short*)d_ws;
    unsigned short* ql = qh + (size_t)B * HW;
    unsigned short* kh = ql + (size_t)B * HW;
    unsigned short* kl = kh + (size_t)B * HW;
    float* attnf = (float*)(kl + (size_t)B * HW);
    unsigned short* attnb = (unsigned short*)(attnf + (size_t)B * H * H);
    unsigned short* vtb = attnb + (size_t)B * H * H;

    qkv_fused_kernel<<<dim3(64, B), 256, 0, stream>>>(x, Wq, bq, Wk, bk, Wv, qh, ql, kh, kl, vtb);
    qk_mfma_kernel<<<256, 256, 0, stream>>>(qh, ql, kh, kl, attnf);
    softmax_kernel<<<(B * H * 64) / 256, 256, 0, stream>>>(attnf, attnb);
    pv_mfma_kernel<<<2048, 256, 0, stream>>>(attnb, vtb, bv, out);
}